// Round 1
// baseline (652.520 us; speedup 1.0000x reference)
//
#include <hip/hip_runtime.h>
#include <hip/hip_bf16.h>

#define CCH 64      // channels
#define NPIX 4096   // 64*64 pooled points
#define TQ 128      // queries per block
#define JC 128      // j-chunk size

// ---------------------------------------------------------------------------
// Kernel 1: avg-pool 4x4 + 1x1 convs -> Q (b,n,8), K (b,n,8), V (b,n,64)
// grid = 8 batches * 64 pooled rows, block = 256
// ---------------------------------------------------------------------------
__global__ __launch_bounds__(256) void pool_qkv_kernel(
    const float* __restrict__ x,
    const float* __restrict__ Wq, const float* __restrict__ bq,
    const float* __restrict__ Wk, const float* __restrict__ bk,
    const float* __restrict__ Wv, const float* __restrict__ bv,
    float* __restrict__ Qo, float* __restrict__ Ko, float* __restrict__ Vo)
{
    const int b  = blockIdx.x >> 6;
    const int ph = blockIdx.x & 63;
    const int t  = threadIdx.x;

    __shared__ float xd[CCH][65];
    __shared__ float sWq[8][CCH], sWk[8][CCH];
    __shared__ float sWv[CCH][CCH];
    __shared__ float sb[80];   // sb[oc]: 0..7 bq, 8..15 bk, 16..79 bv

    for (int i = t; i < 8*CCH; i += 256) { sWq[i>>6][i&63] = Wq[i]; sWk[i>>6][i&63] = Wk[i]; }
    for (int i = t; i < CCH*CCH; i += 256) sWv[i>>6][i&63] = Wv[i];
    if (t < 8)  { sb[t] = bq[t]; sb[8+t] = bk[t]; }
    if (t < 64) sb[16+t] = bv[t];

    // pooling: thread t covers input column w=t of 4 rows, per channel
    const float* xb = x + (size_t)b * CCH * 65536 + (size_t)ph * 4 * 256;
    const int w = t;
    const int pw = w >> 2;
    for (int c = 0; c < CCH; ++c) {
        const float* xr = xb + (size_t)c * 65536;
        float s = xr[w] + xr[256+w] + xr[512+w] + xr[768+w];
        s += __shfl_xor(s, 1);
        s += __shfl_xor(s, 2);
        if ((w & 3) == 0) xd[c][pw] = s * 0.0625f;
    }
    __syncthreads();

    // 80 output channels x 64 points; thread t: point pw2 = t&63, group g = t>>6
    const int pw2 = t & 63;
    const int g = t >> 6;
    const size_t i = (size_t)ph * 64 + pw2;
    for (int u = 0; u < 20; ++u) {
        const int oc = g*20 + u;   // wave-uniform
        const float* wrow = (oc < 8) ? &sWq[oc][0]
                          : (oc < 16) ? &sWk[oc-8][0]
                          : &sWv[oc-16][0];
        float sum = sb[oc];
        #pragma unroll
        for (int c = 0; c < CCH; ++c) sum += wrow[c] * xd[c][pw2];
        if (oc < 8)       Qo[((size_t)b*NPIX + i)*8  + oc]       = sum;
        else if (oc < 16) Ko[((size_t)b*NPIX + i)*8  + (oc-8)]   = sum;
        else              Vo[((size_t)b*NPIX + i)*64 + (oc-16)]  = sum;
    }
}

// ---------------------------------------------------------------------------
// Kernel 2: flash-style attention.
// grid = 8 * (4096/128) = 256 blocks (1 per CU), block = 512 threads.
// Each block: 128 queries; iterate 32 chunks of 128 keys.
// Thread owns query q_own = t>>2, channel block cb = (t&3)*16 -> acc[16].
// OS layout: (b, c, n)
// ---------------------------------------------------------------------------
__global__ __launch_bounds__(512) void attn_kernel(
    const float* __restrict__ Q, const float* __restrict__ K,
    const float* __restrict__ V, float* __restrict__ OS)
{
    const int blk = blockIdx.x;
    const int b   = blk >> 5;
    const int qb  = blk & 31;
    const int i0  = qb * TQ;
    const int t   = threadIdx.x;

    __shared__ float qs[TQ][9];
    __shared__ float ks[JC][9];
    __shared__ __align__(16) float vs[JC][CCH];
    __shared__ float es[JC][TQ+1];          // [j][q], stride 129
    __shared__ float m_s[TQ], l_s[TQ], mn_s[TQ], sc_s[TQ];
    __shared__ float red[4][TQ];

    // load Q tile (1024 floats, contiguous)
    for (int e = t; e < TQ*8; e += 512)
        qs[e>>3][e&7] = Q[((size_t)b*NPIX + i0)*8 + e];
    if (t < TQ) { m_s[t] = -1e30f; l_s[t] = 0.f; }

    const int q_own = t >> 2;
    const int cb    = (t & 3) * 16;
    float acc[16];
    #pragma unroll
    for (int u = 0; u < 16; ++u) acc[u] = 0.f;

    for (int ch = 0; ch < NPIX/JC; ++ch) {
        const int j0 = ch * JC;
        __syncthreads();   // protect ks/vs/es from previous iteration readers

        // --- load K chunk (1024 floats) and V chunk (8192 floats) ---
        for (int e = t; e < JC*8; e += 512)
            ks[e>>3][e&7] = K[((size_t)b*NPIX + j0)*8 + e];
        {
            const float4* src = (const float4*)(V + ((size_t)b*NPIX + j0)*64);
            #pragma unroll
            for (int k = 0; k < 4; ++k) {
                int gidx = k*512 + t;          // 2048 float4s
                float4 v4 = src[gidx];
                int j  = gidx >> 4;
                int c4 = (gidx & 15) * 4;
                *(float4*)&vs[j][c4] = v4;
            }
        }
        __syncthreads();

        // --- energy: e[q][j] = q . k   (128x128 entries) ---
        {
            const int tj = t & 127;
            const int q0 = (t >> 7) * 32;
            float kreg[8];
            #pragma unroll
            for (int d = 0; d < 8; ++d) kreg[d] = ks[tj][d];
            #pragma unroll 4
            for (int qq = 0; qq < 32; ++qq) {
                const int q = q0 + qq;
                float e = 0.f;
                #pragma unroll
                for (int d = 0; d < 8; ++d) e += qs[q][d] * kreg[d];
                es[tj][q] = e;
            }
        }
        __syncthreads();

        // --- chunk row-max per query ---
        {
            const int q = t & 127;
            const int part = t >> 7;
            float mx = -1e30f;
            #pragma unroll 4
            for (int jj = 0; jj < 32; ++jj) mx = fmaxf(mx, es[part*32+jj][q]);
            red[part][q] = mx;
        }
        __syncthreads();

        // --- online max update ---
        if (t < TQ) {
            const int q = t;
            float mc = fmaxf(fmaxf(red[0][q], red[1][q]), fmaxf(red[2][q], red[3][q]));
            float m_old = m_s[q];
            float m_new = fmaxf(m_old, mc);
            mn_s[q] = m_new;
            sc_s[q] = __expf(m_old - m_new);
        }
        __syncthreads();

        // --- p = exp(e - m_new), partial row sums ---
        {
            const int q = t & 127;
            const int part = t >> 7;
            const float mnq = mn_s[q];
            float s = 0.f;
            #pragma unroll 4
            for (int jj = 0; jj < 32; ++jj) {
                const int j = part*32 + jj;
                float p = __expf(es[j][q] - mnq);
                es[j][q] = p;
                s += p;
            }
            red[part][q] = s;
        }
        __syncthreads();

        if (t < TQ) {
            const int q = t;
            l_s[q] = l_s[q] * sc_s[q] + (red[0][q]+red[1][q]+red[2][q]+red[3][q]);
            m_s[q] = mn_s[q];
        }
        // (no barrier needed: PV reads only es/vs/sc_s, all synced above)

        // --- PV accumulate ---
        {
            const float s = sc_s[q_own];
            #pragma unroll
            for (int u = 0; u < 16; ++u) acc[u] *= s;
            #pragma unroll 4
            for (int j = 0; j < JC; ++j) {
                const float p = es[j][q_own];
                const float4 v0 = *(const float4*)&vs[j][cb];
                const float4 v1 = *(const float4*)&vs[j][cb+4];
                const float4 v2 = *(const float4*)&vs[j][cb+8];
                const float4 v3 = *(const float4*)&vs[j][cb+12];
                acc[0]  += p*v0.x; acc[1]  += p*v0.y; acc[2]  += p*v0.z; acc[3]  += p*v0.w;
                acc[4]  += p*v1.x; acc[5]  += p*v1.y; acc[6]  += p*v1.z; acc[7]  += p*v1.w;
                acc[8]  += p*v2.x; acc[9]  += p*v2.y; acc[10] += p*v2.z; acc[11] += p*v2.w;
                acc[12] += p*v3.x; acc[13] += p*v3.y; acc[14] += p*v3.z; acc[15] += p*v3.w;
            }
        }
    }

    __syncthreads();   // l_s final updates visible to all
    const float invl = 1.f / l_s[q_own];
    float* outp = OS + (size_t)b * CCH * NPIX;
    const int i = i0 + q_own;
    #pragma unroll
    for (int u = 0; u < 16; ++u) {
        const int c = cb + u;
        outp[(size_t)c * NPIX + i] = acc[u] * invl;
    }
}

// ---------------------------------------------------------------------------
// Kernel 3: bilinear x4 upsample (align_corners=True) + gamma*up + x
// ---------------------------------------------------------------------------
__global__ __launch_bounds__(256) void upsample_add_kernel(
    const float* __restrict__ OS, const float* __restrict__ x,
    const float* __restrict__ gamma, float* __restrict__ out)
{
    const size_t idx = (size_t)blockIdx.x * 256 + threadIdx.x;
    const float g = gamma[0];
    const int w  = idx & 255;
    const int h  = (int)((idx >> 8) & 255);
    const size_t bc = idx >> 16;

    const float scale = 63.0f / 255.0f;
    float fh = h * scale; int h0 = (int)fh; float fy = fh - (float)h0; int h1 = min(h0+1, 63);
    float fw = w * scale; int w0 = (int)fw; float fx = fw - (float)w0; int w1 = min(w0+1, 63);

    const float* osp = OS + bc * (size_t)NPIX;
    float v00 = osp[h0*64+w0], v01 = osp[h0*64+w1];
    float v10 = osp[h1*64+w0], v11 = osp[h1*64+w1];
    float vt = v00 + (v01 - v00) * fx;
    float vb = v10 + (v11 - v10) * fx;
    float up = vt + (vb - vt) * fy;
    out[idx] = g * up + x[idx];
}

// ---------------------------------------------------------------------------
extern "C" void kernel_launch(void* const* d_in, const int* in_sizes, int n_in,
                              void* d_out, int out_size, void* d_ws, size_t ws_size,
                              hipStream_t stream) {
    const float* x     = (const float*)d_in[0];
    const float* Wq    = (const float*)d_in[1];
    const float* bq    = (const float*)d_in[2];
    const float* Wk    = (const float*)d_in[3];
    const float* bk    = (const float*)d_in[4];
    const float* Wv    = (const float*)d_in[5];
    const float* bv    = (const float*)d_in[6];
    const float* gamma = (const float*)d_in[7];
    float* out = (float*)d_out;

    char* ws = (char*)d_ws;
    float* Qb = (float*)(ws);                       // 8*4096*8*4  = 1 MB
    float* Kb = (float*)(ws + (size_t)(1<<20));     // 1 MB
    float* Vb = (float*)(ws + (size_t)(2<<20));     // 8*4096*64*4 = 8 MB
    float* OS = (float*)(ws + (size_t)(10<<20));    // 8 MB
    // total ws use: 18 MB

    pool_qkv_kernel<<<512, 256, 0, stream>>>(x, Wq, bq, Wk, bk, Wv, bv, Qb, Kb, Vb);
    attn_kernel<<<256, 512, 0, stream>>>(Qb, Kb, Vb, OS);
    const size_t total = (size_t)8 * 64 * 256 * 256;
    upsample_add_kernel<<<(int)(total / 256), 256, 0, stream>>>(OS, x, gamma, out);
}

// Round 2
// 255.944 us; speedup vs baseline: 2.5495x; 2.5495x over previous
//
#include <hip/hip_runtime.h>
#include <hip/hip_bf16.h>

#define CCH 64      // channels
#define NPIX 4096   // 64*64 pooled points
#define TQ 128      // queries per block
#define JC 128      // j-chunk size

typedef __attribute__((ext_vector_type(8))) short short8;   // 8 bf16 (4 VGPRs)
typedef __attribute__((ext_vector_type(16))) float f32x16;  // MFMA 32x32 accumulator

__device__ inline uint32_t pk2bf(float lo, float hi) {
    __hip_bfloat162 h = __float22bfloat162_rn(make_float2(lo, hi));
    return *reinterpret_cast<uint32_t*>(&h);
}

// ---------------------------------------------------------------------------
// Kernel 1: avg-pool 4x4 + 1x1 convs -> Q (b,n,8) f32, K (b,n,8) f32,
//           V transposed (b,c,n) bf16
// ---------------------------------------------------------------------------
__global__ __launch_bounds__(256) void pool_qkv_kernel(
    const float* __restrict__ x,
    const float* __restrict__ Wq, const float* __restrict__ bq,
    const float* __restrict__ Wk, const float* __restrict__ bk,
    const float* __restrict__ Wv, const float* __restrict__ bv,
    float* __restrict__ Qo, float* __restrict__ Ko, __hip_bfloat16* __restrict__ Vo)
{
    const int b  = blockIdx.x >> 6;
    const int ph = blockIdx.x & 63;
    const int t  = threadIdx.x;

    __shared__ float xd[CCH][65];
    __shared__ float sWq[8][CCH], sWk[8][CCH];
    __shared__ float sWv[CCH][CCH];
    __shared__ float sb[80];

    for (int i = t; i < 8*CCH; i += 256) { sWq[i>>6][i&63] = Wq[i]; sWk[i>>6][i&63] = Wk[i]; }
    for (int i = t; i < CCH*CCH; i += 256) sWv[i>>6][i&63] = Wv[i];
    if (t < 8)  { sb[t] = bq[t]; sb[8+t] = bk[t]; }
    if (t < 64) sb[16+t] = bv[t];

    const float* xb = x + (size_t)b * CCH * 65536 + (size_t)ph * 4 * 256;
    const int w = t;
    const int pw = w >> 2;
    for (int c = 0; c < CCH; ++c) {
        const float* xr = xb + (size_t)c * 65536;
        float s = xr[w] + xr[256+w] + xr[512+w] + xr[768+w];
        s += __shfl_xor(s, 1);
        s += __shfl_xor(s, 2);
        if ((w & 3) == 0) xd[c][pw] = s * 0.0625f;
    }
    __syncthreads();

    const int pw2 = t & 63;
    const int g = t >> 6;
    const size_t i = (size_t)ph * 64 + pw2;
    for (int u = 0; u < 20; ++u) {
        const int oc = g*20 + u;   // wave-uniform
        const float* wrow = (oc < 8) ? &sWq[oc][0]
                          : (oc < 16) ? &sWk[oc-8][0]
                          : &sWv[oc-16][0];
        float sum = sb[oc];
        #pragma unroll
        for (int c = 0; c < CCH; ++c) sum += wrow[c] * xd[c][pw2];
        if (oc < 8)       Qo[((size_t)b*NPIX + i)*8  + oc]       = sum;
        else if (oc < 16) Ko[((size_t)b*NPIX + i)*8  + (oc-8)]   = sum;
        else              Vo[((size_t)b*CCH + (oc-16))*NPIX + i] = __float2bfloat16(sum);
    }
}

// ---------------------------------------------------------------------------
// Kernel 2: flash attention with bf16 MFMA PV.
// grid = 256 blocks (8 batches x 32 q-tiles), block = 512 = 8 waves.
// Wave w owns the 32x32 output tile (q rows (w&3)*32, channels (w>>2)*32).
// ---------------------------------------------------------------------------
__global__ __launch_bounds__(512) void attn_kernel(
    const float* __restrict__ Q, const float* __restrict__ K,
    const __hip_bfloat16* __restrict__ V, float* __restrict__ OS)
{
    const int blk  = blockIdx.x;
    const int b    = blk >> 5;
    const int qb   = blk & 31;
    const int i0   = qb * TQ;
    const int t    = threadIdx.x;
    const int lane = t & 63;
    const int w    = t >> 6;

    __shared__ float    qs[TQ][12];     // Q tile, row 48B (16B aligned)
    __shared__ float    ks[JC][12];     // K chunk
    __shared__ uint32_t vs[CCH][68];    // V^T chunk, bf16 pairs (136 bf16/row, 8 pad)
    __shared__ float    es[TQ][132];    // energies [q][j] fp32 (reused as out tile)
    __shared__ uint32_t ps[TQ][68];     // P bf16 pairs [q][j]
    __shared__ float    m_s[TQ], l_s[TQ], mn_s[TQ], sc_s[TQ];
    __shared__ float    red[4][TQ];

    // load Q tile (1024 floats)
    for (int e = t; e < TQ*8; e += 512)
        qs[e>>3][e&7] = Q[((size_t)b*NPIX + i0)*8 + e];
    if (t < TQ) { m_s[t] = -1e30f; l_s[t] = 0.f; }

    f32x16 acc;
    #pragma unroll
    for (int r = 0; r < 16; ++r) acc[r] = 0.f;

    // register prefetch buffers (T14 async-stage split)
    uint4  vreg[2];
    float2 kreg2;

    const int vc0 = t >> 4;        // V stage: row c, 2 rows apart per k
    const int vu  = t & 15;        // 16B-group within row

    auto stage_load = [&](int j0) {
        #pragma unroll
        for (int k = 0; k < 2; ++k) {
            int c = vc0 + k*32;
            vreg[k] = *(const uint4*)(V + ((size_t)(b*CCH + c))*NPIX + j0 + vu*8);
        }
        kreg2 = *(const float2*)(K + ((size_t)b*NPIX + j0)*8 + t*2);
    };
    auto stage_write = [&]() {
        #pragma unroll
        for (int k = 0; k < 2; ++k) {
            int c = vc0 + k*32;
            *(uint4*)&vs[c][vu*4] = vreg[k];
        }
        int e = t*2;
        *(float2*)&ks[e>>3][e&7] = kreg2;
    };

    stage_load(0);

    for (int ch = 0; ch < NPIX/JC; ++ch) {
        __syncthreads();                       // (A) prev chunk's readers done
        stage_write();
        if (ch < NPIX/JC - 1) stage_load((ch+1)*JC);
        __syncthreads();                       // (B) ks/vs ready

        // --- energy: es[q][j] = q . k ---
        {
            const int tj  = t & 127;
            const int qe0 = (t >> 7) * 32;
            float4 k0 = *(const float4*)&ks[tj][0];
            float4 k1 = *(const float4*)&ks[tj][4];
            #pragma unroll 4
            for (int qq = 0; qq < 32; ++qq) {
                const int q = qe0 + qq;
                float4 a0 = *(const float4*)&qs[q][0];
                float4 a1 = *(const float4*)&qs[q][4];
                float e = a0.x*k0.x + a0.y*k0.y + a0.z*k0.z + a0.w*k0.w
                        + a1.x*k1.x + a1.y*k1.y + a1.z*k1.z + a1.w*k1.w;
                es[q][tj] = e;
            }
        }
        __syncthreads();                       // (C) es ready

        // --- chunk row-max partials ---
        {
            const int q = t & 127, part = t >> 7, jb = part*32;
            float mx = -1e30f;
            #pragma unroll
            for (int i = 0; i < 8; ++i) {
                float4 a = *(const float4*)&es[q][jb + i*4];
                mx = fmaxf(mx, fmaxf(fmaxf(a.x, a.y), fmaxf(a.z, a.w)));
            }
            red[part][q] = mx;
        }
        __syncthreads();                       // (D) partials ready

        if (t < TQ) {
            const int q = t;
            float mc = fmaxf(fmaxf(red[0][q], red[1][q]), fmaxf(red[2][q], red[3][q]));
            float m_old = m_s[q];
            float m_new = fmaxf(m_old, mc);
            mn_s[q] = m_new;
            sc_s[q] = __expf(m_old - m_new);
            m_s[q] = m_new;
        }
        __syncthreads();                       // (E) mn_s/sc_s ready

        // --- p = exp(e - m_new) -> bf16, partial row sums ---
        {
            const int q = t & 127, part = t >> 7, jb = part*32;
            const float mnq = mn_s[q];
            float s = 0.f;
            #pragma unroll
            for (int i = 0; i < 4; ++i) {
                float4 a = *(const float4*)&es[q][jb + i*8];
                float4 b2 = *(const float4*)&es[q][jb + i*8 + 4];
                float p0 = __expf(a.x - mnq),  p1 = __expf(a.y - mnq);
                float p2 = __expf(a.z - mnq),  p3 = __expf(a.w - mnq);
                float p4 = __expf(b2.x - mnq), p5 = __expf(b2.y - mnq);
                float p6 = __expf(b2.z - mnq), p7 = __expf(b2.w - mnq);
                s += p0+p1+p2+p3+p4+p5+p6+p7;
                uint4 wv;
                wv.x = pk2bf(p0, p1); wv.y = pk2bf(p2, p3);
                wv.z = pk2bf(p4, p5); wv.w = pk2bf(p6, p7);
                *(uint4*)&ps[q][jb/2 + i*4] = wv;
            }
            red[part][q] = s;
        }
        __syncthreads();                       // (F) ps + sum partials ready

        if (t < TQ) {
            const int q = t;
            l_s[q] = l_s[q] * sc_s[q] + (red[0][q]+red[1][q]+red[2][q]+red[3][q]);
        }

        // --- PV via MFMA 32x32x16 bf16 ---
        {
            const int m0 = (w & 3) * 32;
            const int c0 = (w >> 2) * 32;
            const int lrow = lane & 31, lhi = lane >> 5;
            #pragma unroll
            for (int r = 0; r < 16; ++r) {
                int row = (r&3) + 8*(r>>2) + 4*lhi;
                acc[r] *= sc_s[m0 + row];
            }
            #pragma unroll
            for (int ki = 0; ki < 8; ++ki) {
                short8 afr = *(const short8*)&ps[m0 + lrow][ki*8 + lhi*4];
                short8 bfr = *(const short8*)&vs[c0 + lrow][ki*8 + lhi*4];
                acc = __builtin_amdgcn_mfma_f32_32x32x16_bf16(afr, bfr, acc, 0, 0, 0);
            }
        }
    }

    __syncthreads();    // l_s final; also safe to reuse es as output tile
    {
        const int m0 = (w & 3) * 32;
        const int c0 = (w >> 2) * 32;
        const int lrow = lane & 31, lhi = lane >> 5;
        #pragma unroll
        for (int r = 0; r < 16; ++r) {
            int row = (r&3) + 8*(r>>2) + 4*lhi;
            int q = m0 + row;
            es[c0 + lrow][q] = acc[r] / l_s[q];   // out tile transposed: [c][q]
        }
    }
    __syncthreads();

    // coalesced copy out: OS layout (b, c, n)
    float* outp = OS + (size_t)b * CCH * NPIX + i0;
    #pragma unroll
    for (int e = t; e < CCH*TQ/4; e += 512) {
        int c = e >> 5, pos = (e & 31) * 4;
        *(float4*)(outp + (size_t)c * NPIX + pos) = *(const float4*)&es[c][pos];
    }
}

// ---------------------------------------------------------------------------
// Kernel 3: bilinear x4 upsample (align_corners=True) + gamma*up + x
// ---------------------------------------------------------------------------
__global__ __launch_bounds__(256) void upsample_add_kernel(
    const float* __restrict__ OS, const float* __restrict__ x,
    const float* __restrict__ gamma, float* __restrict__ out)
{
    const size_t idx = (size_t)blockIdx.x * 256 + threadIdx.x;
    const float g = gamma[0];
    const int w  = idx & 255;
    const int h  = (int)((idx >> 8) & 255);
    const size_t bc = idx >> 16;

    const float scale = 63.0f / 255.0f;
    float fh = h * scale; int h0 = (int)fh; float fy = fh - (float)h0; int h1 = min(h0+1, 63);
    float fw = w * scale; int w0 = (int)fw; float fx = fw - (float)w0; int w1 = min(w0+1, 63);

    const float* osp = OS + bc * (size_t)NPIX;
    float v00 = osp[h0*64+w0], v01 = osp[h0*64+w1];
    float v10 = osp[h1*64+w0], v11 = osp[h1*64+w1];
    float vt = v00 + (v01 - v00) * fx;
    float vb = v10 + (v11 - v10) * fx;
    float up = vt + (vb - vt) * fy;
    out[idx] = g * up + x[idx];
}

// ---------------------------------------------------------------------------
extern "C" void kernel_launch(void* const* d_in, const int* in_sizes, int n_in,
                              void* d_out, int out_size, void* d_ws, size_t ws_size,
                              hipStream_t stream) {
    const float* x     = (const float*)d_in[0];
    const float* Wq    = (const float*)d_in[1];
    const float* bq    = (const float*)d_in[2];
    const float* Wk    = (const float*)d_in[3];
    const float* bk    = (const float*)d_in[4];
    const float* Wv    = (const float*)d_in[5];
    const float* bv    = (const float*)d_in[6];
    const float* gamma = (const float*)d_in[7];
    float* out = (float*)d_out;

    char* ws = (char*)d_ws;
    float*          Qb = (float*)(ws);                       // 1 MB
    float*          Kb = (float*)(ws + (size_t)(1<<20));     // 1 MB
    __hip_bfloat16* Vb = (__hip_bfloat16*)(ws + (size_t)(2<<20)); // 4 MB (bf16, transposed)
    float*          OS = (float*)(ws + (size_t)(6<<20));     // 8 MB

    pool_qkv_kernel<<<512, 256, 0, stream>>>(x, Wq, bq, Wk, bk, Wv, bv, Qb, Kb, Vb);
    attn_kernel<<<256, 512, 0, stream>>>(Qb, Kb, Vb, OS);
    const size_t total = (size_t)8 * 64 * 256 * 256;
    upsample_add_kernel<<<(int)(total / 256), 256, 0, stream>>>(OS, x, gamma, out);
}

// Round 3
// 224.271 us; speedup vs baseline: 2.9095x; 1.1412x over previous
//
#include <hip/hip_runtime.h>
#include <hip/hip_bf16.h>

#define CCH 64      // channels
#define NPIX 4096   // 64*64 pooled points

typedef __attribute__((ext_vector_type(8))) short short8;   // 8 bf16 (4 VGPRs)
typedef __attribute__((ext_vector_type(16))) float f32x16;  // MFMA 32x32 accumulator

union U4S8 { uint4 u; short8 s; };

__device__ inline uint32_t pk2bf(float lo, float hi) {
    __hip_bfloat162 h = __float22bfloat162_rn(make_float2(lo, hi));
    return *reinterpret_cast<uint32_t*>(&h);
}

// ---------------------------------------------------------------------------
// Kernel 1: avg-pool 4x4 + 1x1 convs.
//   Q, K: bf16 (b, n, 8)  -- 16B per point, direct MFMA fragment rows
//   V   : bf16 (b, c, n)  -- transposed for PV B-operand reads
// ---------------------------------------------------------------------------
__global__ __launch_bounds__(256) void pool_qkv_kernel(
    const float* __restrict__ x,
    const float* __restrict__ Wq, const float* __restrict__ bq,
    const float* __restrict__ Wk, const float* __restrict__ bk,
    const float* __restrict__ Wv, const float* __restrict__ bv,
    __hip_bfloat16* __restrict__ Qo, __hip_bfloat16* __restrict__ Ko,
    __hip_bfloat16* __restrict__ Vo)
{
    const int b  = blockIdx.x >> 6;
    const int ph = blockIdx.x & 63;
    const int t  = threadIdx.x;

    __shared__ float xd[CCH][65];
    __shared__ float sWq[8][CCH], sWk[8][CCH];
    __shared__ float sWv[CCH][CCH];
    __shared__ float sb[80];

    for (int i = t; i < 8*CCH; i += 256) { sWq[i>>6][i&63] = Wq[i]; sWk[i>>6][i&63] = Wk[i]; }
    for (int i = t; i < CCH*CCH; i += 256) sWv[i>>6][i&63] = Wv[i];
    if (t < 8)  { sb[t] = bq[t]; sb[8+t] = bk[t]; }
    if (t < 64) sb[16+t] = bv[t];

    const float* xb = x + (size_t)b * CCH * 65536 + (size_t)ph * 4 * 256;
    const int w = t;
    const int pw = w >> 2;
    for (int c = 0; c < CCH; ++c) {
        const float* xr = xb + (size_t)c * 65536;
        float s = xr[w] + xr[256+w] + xr[512+w] + xr[768+w];
        s += __shfl_xor(s, 1);
        s += __shfl_xor(s, 2);
        if ((w & 3) == 0) xd[c][pw] = s * 0.0625f;
    }
    __syncthreads();

    const int pw2 = t & 63;
    const int g = t >> 6;
    const size_t i = (size_t)ph * 64 + pw2;
    for (int u = 0; u < 20; ++u) {
        const int oc = g*20 + u;   // wave-uniform
        const float* wrow = (oc < 8) ? &sWq[oc][0]
                          : (oc < 16) ? &sWk[oc-8][0]
                          : &sWv[oc-16][0];
        float sum = sb[oc];
        #pragma unroll
        for (int c = 0; c < CCH; ++c) sum += wrow[c] * xd[c][pw2];
        if (oc < 8)       Qo[((size_t)b*NPIX + i)*8  + oc]       = __float2bfloat16(sum);
        else if (oc < 16) Ko[((size_t)b*NPIX + i)*8  + (oc-8)]   = __float2bfloat16(sum);
        else              Vo[((size_t)b*CCH + (oc-16))*NPIX + i] = __float2bfloat16(sum);
    }
}

// ---------------------------------------------------------------------------
// Kernel 2: flash attention, swapped QK^T, in-register softmax, no main-loop
// barriers. 256 blocks (8 b x 32 q-tiles of 128), 512 thr = 8 waves:
// wave = (qg 0..3) x (kv-half 0..1). Each wave: 32 queries, 2048 kv.
//   S^T = mfma(K_frag, Q_frag)   -> lane holds q = lane&31's 16 of 32 kv
//   PV  = mfma(P_frag, V_frag)   -> P fed in shared-permutation order so
//         P words are plain cvt_pk(p[2w],p[2w+1]); V read at permuted offsets.
// ---------------------------------------------------------------------------
__global__ __launch_bounds__(512) void attn_kernel(
    const __hip_bfloat16* __restrict__ Q, const __hip_bfloat16* __restrict__ K,
    const __hip_bfloat16* __restrict__ V, float* __restrict__ OS)
{
    const int blk  = blockIdx.x;
    const int b    = blk >> 5;
    const int qb   = blk & 31;
    const int i0   = qb * 128;
    const int t    = threadIdx.x;
    const int lane = t & 63;
    const int w    = t >> 6;
    const int qg   = w & 3;
    const int half = w >> 2;
    const int l31  = lane & 31;
    const int hi   = lane >> 5;

    __shared__ __align__(16) float tile0[CCH][132];
    __shared__ __align__(16) float tile1[CCH][132];
    __shared__ __align__(16) float st_m0[128], st_l0[128], st_m1[128], st_l1[128];
    __shared__ __align__(16) float st_f0[128], st_f1[128], st_il[128];

    // Q fragment (B operand): lane holds q = i0+qg*32+l31's 8 dims (hi half zero)
    U4S8 qf;
    if (hi == 0) qf.u = *(const uint4*)(Q + ((size_t)b*NPIX + i0 + qg*32 + l31)*8);
    else         qf.u = make_uint4(0,0,0,0);

    f32x16 acc0, acc1;
    #pragma unroll
    for (int r = 0; r < 16; ++r) { acc0[r] = 0.f; acc1[r] = 0.f; }
    float m = -1e30f, l = 0.f;

    const __hip_bfloat16* Kb = K + (size_t)b*NPIX*8;
    const __hip_bfloat16* Vb = V + (size_t)b*CCH*NPIX;
    const __hip_bfloat16* vrow0 = Vb + (size_t)l31*NPIX;        // c-tile 0 row
    const __hip_bfloat16* vrow1 = Vb + (size_t)(l31+32)*NPIX;   // c-tile 1 row

    const int ch0 = half * 64;
    for (int ch = ch0; ch < ch0 + 64; ++ch) {
        const int kv0 = ch * 32;

        // K fragment (A operand)
        U4S8 kf;
        if (hi == 0) kf.u = *(const uint4*)(Kb + (size_t)(kv0 + l31)*8);
        else         kf.u = make_uint4(0,0,0,0);

        f32x16 zc;
        #pragma unroll
        for (int r = 0; r < 16; ++r) zc[r] = 0.f;
        f32x16 s = __builtin_amdgcn_mfma_f32_32x32x16_bf16(kf.s, qf.s, zc, 0, 0, 0);

        // row max over this lane's 16 kv + partner's 16
        float mx = fmaxf(s[0], s[1]);
        #pragma unroll
        for (int r = 2; r < 16; ++r) mx = fmaxf(mx, s[r]);
        mx = fmaxf(mx, __shfl_xor(mx, 32));

        // deferred rescale (T13): only when chunk max grows past m+8
        if (!__all(mx <= m + 8.f)) {
            float mnew = fmaxf(m, mx);
            float sc = __expf(m - mnew);
            l *= sc;
            m = mnew;
            #pragma unroll
            for (int r = 0; r < 16; ++r) {
                const int qr = (r&3) + 8*(r>>2) + 4*hi;   // q-row of acc[r]
                float scr = __shfl(sc, qr);               // scale lives at lane qr
                acc0[r] *= scr; acc1[r] *= scr;
            }
        }

        float p[16];
        float ssum = 0.f;
        #pragma unroll
        for (int r = 0; r < 16; ++r) { p[r] = __expf(s[r] - m); ssum += p[r]; }
        ssum += __shfl_xor(ssum, 32);
        l += ssum;

        // P fragments: shared kv-permutation sigma(8*hi+j) = 16s+4*hi+(j<4?j:8+j-4)
        // makes A-words plain sequential cvt_pk pairs.
        U4S8 pa0, pa1;
        pa0.u.x = pk2bf(p[0],  p[1]);  pa0.u.y = pk2bf(p[2],  p[3]);
        pa0.u.z = pk2bf(p[4],  p[5]);  pa0.u.w = pk2bf(p[6],  p[7]);
        pa1.u.x = pk2bf(p[8],  p[9]);  pa1.u.y = pk2bf(p[10], p[11]);
        pa1.u.z = pk2bf(p[12], p[13]); pa1.u.w = pk2bf(p[14], p[15]);

        // V fragments at matching permuted offsets: two 8B loads per frag
        U4S8 v00, v01, v10, v11;
        {
            const int o0 = kv0 + 4*hi;        // step 0: kv {4hi..4hi+3, 8+4hi..}
            const int o1 = kv0 + 16 + 4*hi;   // step 1: +16
            uint2 a, c;
            a = *(const uint2*)(vrow0 + o0);     c = *(const uint2*)(vrow0 + o0 + 8);
            v00.u = make_uint4(a.x, a.y, c.x, c.y);
            a = *(const uint2*)(vrow0 + o1);     c = *(const uint2*)(vrow0 + o1 + 8);
            v01.u = make_uint4(a.x, a.y, c.x, c.y);
            a = *(const uint2*)(vrow1 + o0);     c = *(const uint2*)(vrow1 + o0 + 8);
            v10.u = make_uint4(a.x, a.y, c.x, c.y);
            a = *(const uint2*)(vrow1 + o1);     c = *(const uint2*)(vrow1 + o1 + 8);
            v11.u = make_uint4(a.x, a.y, c.x, c.y);
        }

        acc0 = __builtin_amdgcn_mfma_f32_32x32x16_bf16(pa0.s, v00.s, acc0, 0, 0, 0);
        acc1 = __builtin_amdgcn_mfma_f32_32x32x16_bf16(pa0.s, v10.s, acc1, 0, 0, 0);
        acc0 = __builtin_amdgcn_mfma_f32_32x32x16_bf16(pa1.s, v01.s, acc0, 0, 0, 0);
        acc1 = __builtin_amdgcn_mfma_f32_32x32x16_bf16(pa1.s, v11.s, acc1, 0, 0, 0);
    }

    // ---- merge the two kv-halves + transpose + normalize ----
    {
        float (*tile)[132] = half ? tile1 : tile0;
        float* stm = half ? st_m1 : st_m0;
        float* stl = half ? st_l1 : st_l0;
        if (hi == 0) { stm[qg*32 + l31] = m; stl[qg*32 + l31] = l; }
        #pragma unroll
        for (int r = 0; r < 16; ++r) {
            const int qr = (r&3) + 8*(r>>2) + 4*hi;
            tile[l31]     [qg*32 + qr] = acc0[r];
            tile[l31 + 32][qg*32 + qr] = acc1[r];
        }
    }
    __syncthreads();

    if (t < 128) {
        float m0 = st_m0[t], m1 = st_m1[t];
        float l0 = st_l0[t], l1 = st_l1[t];
        float ms = fmaxf(m0, m1);
        float f0 = __expf(m0 - ms), f1 = __expf(m1 - ms);
        st_f0[t] = f0; st_f1[t] = f1;
        st_il[t] = 1.f / (l0*f0 + l1*f1);
    }
    __syncthreads();

    // coalesced combined write: OS (b, c, n)
    float* outp = OS + (size_t)b*CCH*NPIX + i0;
    #pragma unroll
    for (int e = t; e < CCH*128/4; e += 512) {
        const int c = e >> 5, q4 = (e & 31) * 4;
        float4 t0 = *(const float4*)&tile0[c][q4];
        float4 t1 = *(const float4*)&tile1[c][q4];
        float4 f0 = *(const float4*)&st_f0[q4];
        float4 f1 = *(const float4*)&st_f1[q4];
        float4 il = *(const float4*)&st_il[q4];
        float4 o;
        o.x = (t0.x*f0.x + t1.x*f1.x) * il.x;
        o.y = (t0.y*f0.y + t1.y*f1.y) * il.y;
        o.z = (t0.z*f0.z + t1.z*f1.z) * il.z;
        o.w = (t0.w*f0.w + t1.w*f1.w) * il.w;
        *(float4*)(outp + (size_t)c*NPIX + q4) = o;
    }
}

// ---------------------------------------------------------------------------
// Kernel 3: bilinear x4 upsample (align_corners=True) + gamma*up + x
// ---------------------------------------------------------------------------
__global__ __launch_bounds__(256) void upsample_add_kernel(
    const float* __restrict__ OS, const float* __restrict__ x,
    const float* __restrict__ gamma, float* __restrict__ out)
{
    const size_t idx = (size_t)blockIdx.x * 256 + threadIdx.x;
    const float g = gamma[0];
    const int w  = idx & 255;
    const int h  = (int)((idx >> 8) & 255);
    const size_t bc = idx >> 16;

    const float scale = 63.0f / 255.0f;
    float fh = h * scale; int h0 = (int)fh; float fy = fh - (float)h0; int h1 = min(h0+1, 63);
    float fw = w * scale; int w0 = (int)fw; float fx = fw - (float)w0; int w1 = min(w0+1, 63);

    const float* osp = OS + bc * (size_t)NPIX;
    float v00 = osp[h0*64+w0], v01 = osp[h0*64+w1];
    float v10 = osp[h1*64+w0], v11 = osp[h1*64+w1];
    float vt = v00 + (v01 - v00) * fx;
    float vb = v10 + (v11 - v10) * fx;
    float up = vt + (vb - vt) * fy;
    out[idx] = g * up + x[idx];
}

// ---------------------------------------------------------------------------
extern "C" void kernel_launch(void* const* d_in, const int* in_sizes, int n_in,
                              void* d_out, int out_size, void* d_ws, size_t ws_size,
                              hipStream_t stream) {
    const float* x     = (const float*)d_in[0];
    const float* Wq    = (const float*)d_in[1];
    const float* bq    = (const float*)d_in[2];
    const float* Wk    = (const float*)d_in[3];
    const float* bk    = (const float*)d_in[4];
    const float* Wv    = (const float*)d_in[5];
    const float* bv    = (const float*)d_in[6];
    const float* gamma = (const float*)d_in[7];
    float* out = (float*)d_out;

    char* ws = (char*)d_ws;
    __hip_bfloat16* Qb = (__hip_bfloat16*)(ws);                      // 512 KB
    __hip_bfloat16* Kb = (__hip_bfloat16*)(ws + (size_t)( 512<<10)); // 512 KB
    __hip_bfloat16* Vb = (__hip_bfloat16*)(ws + (size_t)(1024<<10)); // 4 MB
    float*          OS = (float*)         (ws + (size_t)(5120<<10)); // 8 MB

    pool_qkv_kernel<<<512, 256, 0, stream>>>(x, Wq, bq, Wk, bk, Wv, bv, Qb, Kb, Vb);
    attn_kernel<<<256, 512, 0, stream>>>(Qb, Kb, Vb, OS);
    const size_t total = (size_t)8 * 64 * 256 * 256;
    upsample_add_kernel<<<(int)(total / 256), 256, 0, stream>>>(OS, x, gamma, out);
}

// Round 4
// 146.452 us; speedup vs baseline: 4.4555x; 1.5314x over previous
//
#include <hip/hip_runtime.h>
#include <hip/hip_bf16.h>

#define CCH 64      // channels
#define NPIX 4096   // 64*64 pooled points

typedef __attribute__((ext_vector_type(8))) short short8;   // 8 bf16 (4 VGPRs)
typedef __attribute__((ext_vector_type(16))) float f32x16;  // MFMA 32x32 accumulator

union U4S8 { uint4 u; short8 s; };

__device__ inline uint32_t pk2bf(float lo, float hi) {
    __hip_bfloat162 h = __float22bfloat162_rn(make_float2(lo, hi));
    return *reinterpret_cast<uint32_t*>(&h);
}

// ---------------------------------------------------------------------------
// Kernel 1: avg-pool 4x4 + 1x1 convs.
//   Q, K: bf16 (b, n, 8)  -- 16B per point, direct MFMA fragment rows
//   VP  : bf16 packed in PV A-fragment order:
//         frag id = ((chunk*2 + kstep)*2 + ctile), 512 bf16 per frag,
//         frag[lane*8 + el] = V[c = 32*ctile + (lane&31)]
//                              [kv = 32*chunk + 16*kstep + 8*(lane>>5) + el]
// ---------------------------------------------------------------------------
__global__ __launch_bounds__(256) void pool_qkv_kernel(
    const float* __restrict__ x,
    const float* __restrict__ Wq, const float* __restrict__ bq,
    const float* __restrict__ Wk, const float* __restrict__ bk,
    const float* __restrict__ Wv, const float* __restrict__ bv,
    __hip_bfloat16* __restrict__ Qo, __hip_bfloat16* __restrict__ Ko,
    __hip_bfloat16* __restrict__ VPo)
{
    const int b  = blockIdx.x >> 6;
    const int ph = blockIdx.x & 63;
    const int t  = threadIdx.x;

    __shared__ float xd[CCH][65];
    __shared__ float sWq[8][CCH], sWk[8][CCH];
    __shared__ float sWv[CCH][CCH];
    __shared__ float sb[80];

    for (int i = t; i < 8*CCH; i += 256) { sWq[i>>6][i&63] = Wq[i]; sWk[i>>6][i&63] = Wk[i]; }
    for (int i = t; i < CCH*CCH; i += 256) sWv[i>>6][i&63] = Wv[i];
    if (t < 8)  { sb[t] = bq[t]; sb[8+t] = bk[t]; }
    if (t < 64) sb[16+t] = bv[t];

    const float* xb = x + (size_t)b * CCH * 65536 + (size_t)ph * 4 * 256;
    const int w = t;
    const int pw = w >> 2;
    for (int c = 0; c < CCH; ++c) {
        const float* xr = xb + (size_t)c * 65536;
        float s = xr[w] + xr[256+w] + xr[512+w] + xr[768+w];
        s += __shfl_xor(s, 1);
        s += __shfl_xor(s, 2);
        if ((w & 3) == 0) xd[c][pw] = s * 0.0625f;
    }
    __syncthreads();

    const int pw2 = t & 63;
    const int g = t >> 6;
    const int i = ph * 64 + pw2;
    for (int u = 0; u < 20; ++u) {
        const int oc = g*20 + u;   // wave-uniform
        const float* wrow = (oc < 8) ? &sWq[oc][0]
                          : (oc < 16) ? &sWk[oc-8][0]
                          : &sWv[oc-16][0];
        float sum = sb[oc];
        #pragma unroll
        for (int c = 0; c < CCH; ++c) sum += wrow[c] * xd[c][pw2];
        if (oc < 8)       Qo[((size_t)b*NPIX + i)*8  + oc]       = __float2bfloat16(sum);
        else if (oc < 16) Ko[((size_t)b*NPIX + i)*8  + (oc-8)]   = __float2bfloat16(sum);
        else {
            const int c  = oc - 16;
            const int chg = i >> 5, s1 = (i>>4)&1, h2 = (i>>3)&1, el = i&7;
            const int ct = c >> 5;
            VPo[(((size_t)b*512 + (size_t)((chg*2 + s1)*2 + ct))*512)
                + (h2*32 + (c&31))*8 + el] = __float2bfloat16(sum);
        }
    }
}

// ---------------------------------------------------------------------------
// Kernel 2: flash attention. 1024 blocks (xcd-mapped: b = blk&7), 256 thr =
// 4 waves = 4 kv-quarters; each block covers 32 queries.
//   S^T = mfma(K_frag, Q_frag): lane (q=l&31) holds 16 of 32 kv scores.
//   PV  = mfma(V_frag(A, packed coalesced), P_frag(B via half-exchange)):
//         D[row=c][col=q], all 16 acc values belong to lane's own query.
// 4-way kv merge through LDS at the end.
// ---------------------------------------------------------------------------
__global__ __launch_bounds__(256, 4) void attn_kernel(
    const __hip_bfloat16* __restrict__ Q, const __hip_bfloat16* __restrict__ K,
    const __hip_bfloat16* __restrict__ VP, float* __restrict__ OS)
{
    const int bb   = blockIdx.x;
    const int b    = bb & 7;          // XCD-locality: batch per XCD
    const int qg   = bb >> 3;         // 0..127
    const int i0   = qg * 32;
    const int t    = threadIdx.x;
    const int lane = t & 63;
    const int kvq  = t >> 6;          // wave = kv quarter
    const int l31  = lane & 31;
    const int hi   = lane >> 5;

    __shared__ float tiles[4][64][33];
    __shared__ float ml[4][2][32];
    __shared__ float fs[4][32];
    __shared__ float ils[32];

    // Q fragment (B operand): hi=0 lanes hold Q[q=i0+l31][d=0..7], hi=1 zero
    U4S8 qf;
    if (hi == 0) qf.u = *(const uint4*)(Q + ((size_t)b*NPIX + i0 + l31)*8);
    else         qf.u = make_uint4(0,0,0,0);

    f32x16 acc0, acc1, zacc;
    #pragma unroll
    for (int r = 0; r < 16; ++r) { acc0[r] = 0.f; acc1[r] = 0.f; zacc[r] = 0.f; }
    float m = -1e30f, l = 0.f;

    const __hip_bfloat16* Kb  = K  + (size_t)b*NPIX*8;
    const __hip_bfloat16* VPb = VP + (size_t)b*512*512;   // 512 frags x 512 bf16

    auto ldK = [&](int kv) {
        U4S8 r;
        if (hi == 0) r.u = *(const uint4*)(Kb + (size_t)(kv + l31)*8);
        else         r.u = make_uint4(0,0,0,0);
        return r;
    };
    auto ldVP = [&](int chg, int s1, int ct) {
        U4S8 r;
        r.u = *(const uint4*)(VPb + ((size_t)((chg*2 + s1)*2 + ct))*512 + lane*8);
        return r;
    };

    int kv0 = kvq * 1024;
    // prefetch chunk 0
    U4S8 kf = ldK(kv0);
    U4S8 v00 = ldVP(kv0>>5, 0, 0), v10 = ldVP(kv0>>5, 0, 1);
    U4S8 v01 = ldVP(kv0>>5, 1, 0), v11 = ldVP(kv0>>5, 1, 1);

    #pragma unroll 1
    for (int ch = 0; ch < 32; ++ch) {
        U4S8 ckf = kf, cv00 = v00, cv01 = v01, cv10 = v10, cv11 = v11;
        const int nkv0 = kv0 + 32;
        // prefetch next chunk (reads past quarter stay inside d_ws; unused on last iter)
        kf  = ldK(nkv0);
        v00 = ldVP(nkv0>>5, 0, 0); v10 = ldVP(nkv0>>5, 0, 1);
        v01 = ldVP(nkv0>>5, 1, 0); v11 = ldVP(nkv0>>5, 1, 1);

        // S^T: lane holds q=l31, kv rows (r&3)+8*(r>>2)+4*hi of this 32-chunk
        f32x16 s = __builtin_amdgcn_mfma_f32_32x32x16_bf16(ckf.s, qf.s, zacc, 0, 0, 0);

        float mx = fmaxf(s[0], s[1]);
        #pragma unroll
        for (int r = 2; r < 16; ++r) mx = fmaxf(mx, s[r]);
        mx = fmaxf(mx, __shfl_xor(mx, 32));

        // deferred rescale (T13): all acc cols are lane's own query -> plain scale
        if (!__all(mx <= m + 8.f)) {
            float mnew = fmaxf(m, mx);
            float sc = __expf(m - mnew);
            l *= sc; m = mnew;
            #pragma unroll
            for (int r = 0; r < 16; ++r) { acc0[r] *= sc; acc1[r] *= sc; }
        }

        float p[16];
        float ssum = 0.f;
        #pragma unroll
        for (int r = 0; r < 16; ++r) { p[r] = __expf(s[r] - m); ssum += p[r]; }
        ssum += __shfl_xor(ssum, 32);
        l += ssum;

        // B-operand P fragments: lane (l31,hi) needs P[q=l31][kv=16s+8hi+j].
        // Own p[] holds kv {4hi+0..3, 8+4hi+0..3, 16+..., 24+...}; partner half
        // supplies the other quads via shfl_xor(32).
        uint32_t W01 = pk2bf(p[0],  p[1]),  W23 = pk2bf(p[2],  p[3]);
        uint32_t W45 = pk2bf(p[4],  p[5]),  W67 = pk2bf(p[6],  p[7]);
        uint32_t W89 = pk2bf(p[8],  p[9]),  Wab = pk2bf(p[10], p[11]);
        uint32_t Wcd = pk2bf(p[12], p[13]), Wef = pk2bf(p[14], p[15]);
        uint32_t W45p = (uint32_t)__shfl_xor((int)W45, 32);
        uint32_t W67p = (uint32_t)__shfl_xor((int)W67, 32);
        uint32_t W01p = (uint32_t)__shfl_xor((int)W01, 32);
        uint32_t W23p = (uint32_t)__shfl_xor((int)W23, 32);
        uint32_t Wcdp = (uint32_t)__shfl_xor((int)Wcd, 32);
        uint32_t Wefp = (uint32_t)__shfl_xor((int)Wef, 32);
        uint32_t W89p = (uint32_t)__shfl_xor((int)W89, 32);
        uint32_t Wabp = (uint32_t)__shfl_xor((int)Wab, 32);
        U4S8 pb0, pb1;
        pb0.u.x = hi ? W45p : W01;   pb0.u.y = hi ? W67p : W23;
        pb0.u.z = hi ? W45  : W01p;  pb0.u.w = hi ? W67  : W23p;
        pb1.u.x = hi ? Wcdp : W89;   pb1.u.y = hi ? Wefp : Wab;
        pb1.u.z = hi ? Wcd  : W89p;  pb1.u.w = hi ? Wef  : Wabp;

        acc0 = __builtin_amdgcn_mfma_f32_32x32x16_bf16(cv00.s, pb0.s, acc0, 0, 0, 0);
        acc1 = __builtin_amdgcn_mfma_f32_32x32x16_bf16(cv10.s, pb0.s, acc1, 0, 0, 0);
        acc0 = __builtin_amdgcn_mfma_f32_32x32x16_bf16(cv01.s, pb1.s, acc0, 0, 0, 0);
        acc1 = __builtin_amdgcn_mfma_f32_32x32x16_bf16(cv11.s, pb1.s, acc1, 0, 0, 0);

        kv0 = nkv0;
    }

    // ---- 4-way kv merge ----
    #pragma unroll
    for (int r = 0; r < 16; ++r) {
        const int cr = (r&3) + 8*(r>>2) + 4*hi;
        tiles[kvq][cr]     [l31] = acc0[r];
        tiles[kvq][cr + 32][l31] = acc1[r];
    }
    if (hi == 0) { ml[kvq][0][l31] = m; ml[kvq][1][l31] = l; }
    __syncthreads();

    if (t < 32) {
        float m0 = ml[0][0][t], m1 = ml[1][0][t], m2 = ml[2][0][t], m3 = ml[3][0][t];
        float ms = fmaxf(fmaxf(m0, m1), fmaxf(m2, m3));
        float f0 = __expf(m0-ms), f1 = __expf(m1-ms), f2 = __expf(m2-ms), f3 = __expf(m3-ms);
        fs[0][t] = f0; fs[1][t] = f1; fs[2][t] = f2; fs[3][t] = f3;
        ils[t] = 1.f / (ml[0][1][t]*f0 + ml[1][1][t]*f1 + ml[2][1][t]*f2 + ml[3][1][t]*f3);
    }
    __syncthreads();

    // combine + write: OS (b, c, n); thread -> (c = t>>2, 8 queries)
    float* outp = OS + (size_t)b*CCH*NPIX + i0;
    const int c  = t >> 2;
    const int q8 = (t & 3) * 8;
    float o[8];
    #pragma unroll
    for (int j = 0; j < 8; ++j) {
        const int q = q8 + j;
        float v = tiles[0][c][q]*fs[0][q] + tiles[1][c][q]*fs[1][q]
                + tiles[2][c][q]*fs[2][q] + tiles[3][c][q]*fs[3][q];
        o[j] = v * ils[q];
    }
    *(float4*)(outp + (size_t)c*NPIX + q8)     = make_float4(o[0], o[1], o[2], o[3]);
    *(float4*)(outp + (size_t)c*NPIX + q8 + 4) = make_float4(o[4], o[5], o[6], o[7]);
}

// ---------------------------------------------------------------------------
// Kernel 3: bilinear x4 upsample (align_corners=True) + gamma*up + x
// ---------------------------------------------------------------------------
__global__ __launch_bounds__(256) void upsample_add_kernel(
    const float* __restrict__ OS, const float* __restrict__ x,
    const float* __restrict__ gamma, float* __restrict__ out)
{
    const size_t idx = (size_t)blockIdx.x * 256 + threadIdx.x;
    const float g = gamma[0];
    const int w  = idx & 255;
    const int h  = (int)((idx >> 8) & 255);
    const size_t bc = idx >> 16;

    const float scale = 63.0f / 255.0f;
    float fh = h * scale; int h0 = (int)fh; float fy = fh - (float)h0; int h1 = min(h0+1, 63);
    float fw = w * scale; int w0 = (int)fw; float fx = fw - (float)w0; int w1 = min(w0+1, 63);

    const float* osp = OS + bc * (size_t)NPIX;
    float v00 = osp[h0*64+w0], v01 = osp[h0*64+w1];
    float v10 = osp[h1*64+w0], v11 = osp[h1*64+w1];
    float vt = v00 + (v01 - v00) * fx;
    float vb = v10 + (v11 - v10) * fx;
    float up = vt + (vb - vt) * fy;
    out[idx] = g * up + x[idx];
}

// ---------------------------------------------------------------------------
extern "C" void kernel_launch(void* const* d_in, const int* in_sizes, int n_in,
                              void* d_out, int out_size, void* d_ws, size_t ws_size,
                              hipStream_t stream) {
    const float* x     = (const float*)d_in[0];
    const float* Wq    = (const float*)d_in[1];
    const float* bq    = (const float*)d_in[2];
    const float* Wk    = (const float*)d_in[3];
    const float* bk    = (const float*)d_in[4];
    const float* Wv    = (const float*)d_in[5];
    const float* bv    = (const float*)d_in[6];
    const float* gamma = (const float*)d_in[7];
    float* out = (float*)d_out;

    char* ws = (char*)d_ws;
    __hip_bfloat16* Qb = (__hip_bfloat16*)(ws);                      // 512 KB
    __hip_bfloat16* Kb = (__hip_bfloat16*)(ws + (size_t)( 512<<10)); // 512 KB
    __hip_bfloat16* VP = (__hip_bfloat16*)(ws + (size_t)(1024<<10)); // 4 MB packed
    float*          OS = (float*)         (ws + (size_t)(5120<<10)); // 8 MB

    pool_qkv_kernel<<<512, 256, 0, stream>>>(x, Wq, bq, Wk, bk, Wv, bv, Qb, Kb, VP);
    attn_kernel<<<1024, 256, 0, stream>>>(Qb, Kb, VP, OS);
    const size_t total = (size_t)8 * 64 * 256 * 256;
    upsample_add_kernel<<<(int)(total / 256), 256, 0, stream>>>(OS, x, gamma, out);
}